// Round 1
// baseline (676.820 us; speedup 1.0000x reference)
//
#include <hip/hip_runtime.h>
#include <hip/hip_bf16.h>

#define HN 128      // hidden size
#define TSTEPS 250
#define ON 20       // output size
#define GK 700      // input size
#define TKK 28      // GEMM K tile (700 = 25*28 exactly)

// ---------------------------------------------------------------------------
// Phase A: in1_ff[bt, h] = X[bt, :] . W_ih1[h, :] + b_ih1[h]
// M = 64000, N = 128, K = 700. fp32 vector GEMM, 128x128 tile, TK=28.
// ---------------------------------------------------------------------------
__global__ __launch_bounds__(256) void ff_gemm(const float* __restrict__ X,
                                               const float* __restrict__ W,
                                               const float* __restrict__ bias,
                                               float* __restrict__ out) {
    __shared__ __align__(16) float Xs[TKK][HN];
    __shared__ __align__(16) float Ws[TKK][HN];
    const int tid = threadIdx.x;
    const int tx = tid & 15;
    const int ty = tid >> 4;
    const int m0 = blockIdx.x * 128;

    float acc[8][8];
#pragma unroll
    for (int i = 0; i < 8; ++i)
#pragma unroll
        for (int n = 0; n < 8; ++n) acc[i][n] = 0.f;

    for (int k0 = 0; k0 < GK; k0 += TKK) {
        __syncthreads();
        // stage: 7 float4 per row, 128 rows each operand; lanes map to
        // consecutive rows -> conflict-free LDS writes (k-major transpose).
        for (int idx = tid; idx < 7 * 128; idx += 256) {
            const int kb = idx >> 7;   // 0..6
            const int r  = idx & 127;
            float4 v = *(const float4*)&X[(size_t)(m0 + r) * GK + k0 + kb * 4];
            Xs[kb * 4 + 0][r] = v.x;
            Xs[kb * 4 + 1][r] = v.y;
            Xs[kb * 4 + 2][r] = v.z;
            Xs[kb * 4 + 3][r] = v.w;
            float4 w = *(const float4*)&W[(size_t)r * GK + k0 + kb * 4];
            Ws[kb * 4 + 0][r] = w.x;
            Ws[kb * 4 + 1][r] = w.y;
            Ws[kb * 4 + 2][r] = w.z;
            Ws[kb * 4 + 3][r] = w.w;
        }
        __syncthreads();
#pragma unroll
        for (int k = 0; k < TKK; ++k) {
            float a[8], b[8];
            *(float4*)&a[0] = *(const float4*)&Xs[k][ty * 8];
            *(float4*)&a[4] = *(const float4*)&Xs[k][ty * 8 + 4];
            *(float4*)&b[0] = *(const float4*)&Ws[k][tx * 8];
            *(float4*)&b[4] = *(const float4*)&Ws[k][tx * 8 + 4];
#pragma unroll
            for (int i = 0; i < 8; ++i)
#pragma unroll
                for (int n = 0; n < 8; ++n)
                    acc[i][n] = fmaf(a[i], b[n], acc[i][n]);
        }
    }

    float bv[8];
    *(float4*)&bv[0] = *(const float4*)&bias[tx * 8];
    *(float4*)&bv[4] = *(const float4*)&bias[tx * 8 + 4];
#pragma unroll
    for (int i = 0; i < 8; ++i) {
        const size_t row = (size_t)(m0 + ty * 8 + i);
        float4 v0, v1;
        v0.x = acc[i][0] + bv[0]; v0.y = acc[i][1] + bv[1];
        v0.z = acc[i][2] + bv[2]; v0.w = acc[i][3] + bv[3];
        v1.x = acc[i][4] + bv[4]; v1.y = acc[i][5] + bv[5];
        v1.z = acc[i][6] + bv[6]; v1.w = acc[i][7] + bv[7];
        *(float4*)&out[row * HN + tx * 8]     = v0;
        *(float4*)&out[row * HN + tx * 8 + 4] = v1;
    }
}

// ---------------------------------------------------------------------------
// Phase B: recurrent dynamics. One workgroup (256 threads) per batch row.
// Recurrent weights held in VGPRs (64 floats per thread per matrix; thread
// (j = tid&127, h = tid>>7) owns W[j][64h .. 64h+63]). Spikes broadcast
// through LDS. 250 sequential steps, ~6 barriers/step.
// ---------------------------------------------------------------------------
__global__ __launch_bounds__(256, 1) void srnn_rec(
    const float* __restrict__ ff,
    const float* __restrict__ W_h1h1, const float* __restrict__ b_h1h1,
    const float* __restrict__ W_h1h2, const float* __restrict__ b_h1h2,
    const float* __restrict__ W_h2h2, const float* __restrict__ b_h2h2,
    const float* __restrict__ W_h2o,  const float* __restrict__ b_h2o,
    const float* __restrict__ tau_adp_h1, const float* __restrict__ tau_adp_h2,
    const float* __restrict__ tau_m_h1,   const float* __restrict__ tau_m_h2,
    const float* __restrict__ tau_m_o,
    const float* __restrict__ h1m0, const float* __restrict__ h2m0,
    const float* __restrict__ om0,
    float* __restrict__ out) {
    const int b   = blockIdx.x;
    const int tid = threadIdx.x;
    const int j   = tid & 127;
    const int h   = tid >> 7;   // wave-uniform (waves 0,1 -> 0; waves 2,3 -> 1)

    __shared__ __align__(16) float s1_lds[HN];
    __shared__ __align__(16) float s2_lds[HN];
    __shared__ float part1[HN];
    __shared__ float partB[HN];
    __shared__ float partC[HN];
    __shared__ float ro_part[160];
    __shared__ float om_lds[ON];

    // ---- load weight registers -------------------------------------------
    float wA[64], wB[64], wC[64];
    {
        const float* pA = W_h1h1 + j * HN + h * 64;
        const float* pB = W_h1h2 + j * HN + h * 64;
        const float* pC = W_h2h2 + j * HN + h * 64;
#pragma unroll
        for (int kk = 0; kk < 64; kk += 4) {
            *(float4*)&wA[kk] = *(const float4*)&pA[kk];
            *(float4*)&wB[kk] = *(const float4*)&pB[kk];
            *(float4*)&wC[kk] = *(const float4*)&pC[kk];
        }
    }
    const int o_ro = tid >> 3;   // 0..31 (only <20 used)
    const int seg  = tid & 7;
    float wO[16];
    if (tid < 160) {
#pragma unroll
        for (int m = 0; m < 16; m += 4)
            *(float4*)&wO[m] = *(const float4*)&W_h2o[o_ro * HN + seg * 16 + m];
    }

    // ---- state ------------------------------------------------------------
    float h1m = 0.f, b1 = 0.01f, s1 = 0.f;
    float h2m = 0.f, b2 = 0.01f, s2 = 0.f;
    float a1 = 0.f, r1 = 0.f, a2 = 0.f, r2 = 0.f, bh1 = 0.f, bh12 = 0.f, bh22 = 0.f;
    if (tid < HN) {
        h1m = h1m0[b * HN + j];
        h2m = h2m0[b * HN + j];
        a1 = expf(-1.f / tau_m_h1[j]);
        r1 = expf(-1.f / tau_adp_h1[j]);
        a2 = expf(-1.f / tau_m_h2[j]);
        r2 = expf(-1.f / tau_adp_h2[j]);
        bh1  = b_h1h1[j];
        bh12 = b_h1h2[j];
        bh22 = b_h2h2[j];
        s1_lds[j] = 0.f;
        s2_lds[j] = 0.f;
    }
    float om = 0.f, ao = 0.f, accum = 0.f, bo = 0.f;
    if (tid < ON) {
        om = om0[b * ON + tid];
        ao = expf(-1.f / tau_m_o[tid]);
        bo = b_h2o[tid];
    }
    __syncthreads();

    const float* ffp = ff + (size_t)b * TSTEPS * HN + j;
    float ff_cur = (tid < HN) ? ffp[0] : 0.f;

    for (int t = 0; t < TSTEPS; ++t) {
        // prefetch next step's feedforward drive (consumed next iteration)
        float ff_next = 0.f;
        if (tid < HN && t + 1 < TSTEPS) ff_next = ffp[(size_t)(t + 1) * HN];

        // phase 1: matvecs on OLD spikes: W_h1h1 . s1 and W_h2h2 . s2
        float pA0 = 0.f, pA1 = 0.f, pC0 = 0.f, pC1 = 0.f;
#pragma unroll
        for (int kk = 0; kk < 64; kk += 4) {
            float4 sa = *(const float4*)&s1_lds[h * 64 + kk];
            float4 sc = *(const float4*)&s2_lds[h * 64 + kk];
            pA0 = fmaf(sa.x, wA[kk],     pA0);
            pA1 = fmaf(sa.y, wA[kk + 1], pA1);
            pA0 = fmaf(sa.z, wA[kk + 2], pA0);
            pA1 = fmaf(sa.w, wA[kk + 3], pA1);
            pC0 = fmaf(sc.x, wC[kk],     pC0);
            pC1 = fmaf(sc.y, wC[kk + 1], pC1);
            pC0 = fmaf(sc.z, wC[kk + 2], pC0);
            pC1 = fmaf(sc.w, wC[kk + 3], pC1);
        }
        const float pA = pA0 + pA1;
        const float pC = pC0 + pC1;
        if (h) { part1[j] = pA; partC[j] = pC; }
        __syncthreads();

        // phase 2: layer-1 LIF update + spike
        if (tid < HN) {
            const float in1 = ff_cur + bh1 + pA + part1[j];
            b1 = r1 * b1 + (1.f - r1) * s1;
            const float Bth = 0.01f + 1.8f * b1;
            h1m = h1m * a1 + (1.f - a1) * in1 - Bth * s1;
            s1 = (h1m - Bth > 0.f) ? 1.f : 0.f;
            s1_lds[j] = s1;
        }
        __syncthreads();

        // phase 3: matvec on NEW s1: W_h1h2 . s1
        float pB0 = 0.f, pB1 = 0.f, pB2 = 0.f, pB3 = 0.f;
#pragma unroll
        for (int kk = 0; kk < 64; kk += 4) {
            float4 sb = *(const float4*)&s1_lds[h * 64 + kk];
            pB0 = fmaf(sb.x, wB[kk],     pB0);
            pB1 = fmaf(sb.y, wB[kk + 1], pB1);
            pB2 = fmaf(sb.z, wB[kk + 2], pB2);
            pB3 = fmaf(sb.w, wB[kk + 3], pB3);
        }
        const float pB = (pB0 + pB1) + (pB2 + pB3);
        if (h) partB[j] = pB;
        __syncthreads();

        // phase 4: layer-2 LIF update + spike
        if (tid < HN) {
            const float pCfull = pC + partC[j];
            const float in2 = pB + partB[j] + bh12 + pCfull + bh22;
            b2 = r2 * b2 + (1.f - r2) * s2;
            const float Bth = 0.01f + 1.8f * b2;
            h2m = h2m * a2 + (1.f - a2) * in2 - Bth * s2;
            s2 = (h2m - Bth > 0.f) ? 1.f : 0.f;
            s2_lds[j] = s2;
        }
        __syncthreads();

        // phase 5: readout partials (threads 0..159: o = tid>>3, seg = tid&7)
        if (tid < 160) {
            float p = 0.f;
#pragma unroll
            for (int m = 0; m < 16; ++m)
                p = fmaf(s2_lds[seg * 16 + m], wO[m], p);
            ro_part[tid] = p;
        }
        __syncthreads();

        // phase 6: leaky-integrator readout
        if (tid < ON) {
            float r = bo;
#pragma unroll
            for (int g = 0; g < 8; ++g) r += ro_part[tid * 8 + g];
            om = om * ao + (1.f - ao) * r;
            om_lds[tid] = om;
        }
        __syncthreads();

        // phase 7: softmax accumulate (t > 10)
        if (tid < ON && t > 10) {
            float mx = om_lds[0];
#pragma unroll
            for (int k = 1; k < ON; ++k) mx = fmaxf(mx, om_lds[k]);
            float den = 0.f;
#pragma unroll
            for (int k = 0; k < ON; ++k) den += expf(om_lds[k] - mx);
            accum += expf(om - mx) / den;
        }
        ff_cur = ff_next;
    }

    if (tid < ON) out[b * ON + tid] = accum;
}

// ---------------------------------------------------------------------------
// Phase C: A_norm = sum|W_h1h1| + sum|W_h2h2|  -> out[5120]
// ---------------------------------------------------------------------------
__global__ void anorm_kernel(const float* __restrict__ W1,
                             const float* __restrict__ W2,
                             float* __restrict__ out) {
    __shared__ float red[256];
    float s = 0.f;
    for (int i = threadIdx.x; i < HN * HN; i += 256)
        s += fabsf(W1[i]) + fabsf(W2[i]);
    red[threadIdx.x] = s;
    __syncthreads();
    for (int off = 128; off > 0; off >>= 1) {
        if (threadIdx.x < off) red[threadIdx.x] += red[threadIdx.x + off];
        __syncthreads();
    }
    if (threadIdx.x == 0) out[256 * ON] = red[0];
}

extern "C" void kernel_launch(void* const* d_in, const int* in_sizes, int n_in,
                              void* d_out, int out_size, void* d_ws, size_t ws_size,
                              hipStream_t stream) {
    const float* input      = (const float*)d_in[0];
    // d_in[1], d_in[2]: A1_mask/A2_mask -- all-ones, unused by reference math
    const float* W_ih1      = (const float*)d_in[3];
    const float* b_ih1      = (const float*)d_in[4];
    const float* W_h1h1     = (const float*)d_in[5];
    const float* b_h1h1     = (const float*)d_in[6];
    const float* W_h1h2     = (const float*)d_in[7];
    const float* b_h1h2     = (const float*)d_in[8];
    const float* W_h2h2     = (const float*)d_in[9];
    const float* b_h2h2     = (const float*)d_in[10];
    const float* W_h2o      = (const float*)d_in[11];
    const float* b_h2o      = (const float*)d_in[12];
    const float* tau_adp_h1 = (const float*)d_in[13];
    const float* tau_adp_h2 = (const float*)d_in[14];
    const float* tau_m_h1   = (const float*)d_in[15];
    const float* tau_m_h2   = (const float*)d_in[16];
    const float* tau_m_o    = (const float*)d_in[17];
    const float* h1m0       = (const float*)d_in[18];
    const float* h2m0       = (const float*)d_in[19];
    const float* om0        = (const float*)d_in[20];

    float* out   = (float*)d_out;
    float* ffbuf = (float*)d_ws;   // needs 256*250*128*4 = 32.768 MB

    // Phase A: feedforward GEMM (64000 x 128 over K=700)
    ff_gemm<<<500, 256, 0, stream>>>(input, W_ih1, b_ih1, ffbuf);
    // Phase B: 250-step recurrence, one WG per batch row
    srnn_rec<<<256, 256, 0, stream>>>(ffbuf, W_h1h1, b_h1h1, W_h1h2, b_h1h2,
                                      W_h2h2, b_h2h2, W_h2o, b_h2o,
                                      tau_adp_h1, tau_adp_h2,
                                      tau_m_h1, tau_m_h2, tau_m_o,
                                      h1m0, h2m0, om0, out);
    // Phase C: A_norm scalar
    anorm_kernel<<<1, 256, 0, stream>>>(W_h1h1, W_h2h2, out);
}

// Round 2
// 424.999 us; speedup vs baseline: 1.5925x; 1.5925x over previous
//
#include <hip/hip_runtime.h>
#include <hip/hip_bf16.h>

#define HN 128      // hidden size
#define TSTEPS 250
#define ON 20       // output size
#define GK 700      // input size
#define TKK 28      // GEMM K tile (700 = 25*28 exactly)

// ---------------------------------------------------------------------------
// Phase A: in1_ff[bt, h] = X[bt, :] . W_ih1[h, :] + b_ih1[h]
// M = 64000, N = 128, K = 700. fp32 vector GEMM, 128x128 tile, TK=28.
// ---------------------------------------------------------------------------
__global__ __launch_bounds__(256) void ff_gemm(const float* __restrict__ X,
                                               const float* __restrict__ W,
                                               const float* __restrict__ bias,
                                               float* __restrict__ out) {
    __shared__ __align__(16) float Xs[TKK][HN];
    __shared__ __align__(16) float Ws[TKK][HN];
    const int tid = threadIdx.x;
    const int tx = tid & 15;
    const int ty = tid >> 4;
    const int m0 = blockIdx.x * 128;

    float acc[8][8];
#pragma unroll
    for (int i = 0; i < 8; ++i)
#pragma unroll
        for (int n = 0; n < 8; ++n) acc[i][n] = 0.f;

    for (int k0 = 0; k0 < GK; k0 += TKK) {
        __syncthreads();
        for (int idx = tid; idx < 7 * 128; idx += 256) {
            const int kb = idx >> 7;   // 0..6
            const int r  = idx & 127;
            float4 v = *(const float4*)&X[(size_t)(m0 + r) * GK + k0 + kb * 4];
            Xs[kb * 4 + 0][r] = v.x;
            Xs[kb * 4 + 1][r] = v.y;
            Xs[kb * 4 + 2][r] = v.z;
            Xs[kb * 4 + 3][r] = v.w;
            float4 w = *(const float4*)&W[(size_t)r * GK + k0 + kb * 4];
            Ws[kb * 4 + 0][r] = w.x;
            Ws[kb * 4 + 1][r] = w.y;
            Ws[kb * 4 + 2][r] = w.z;
            Ws[kb * 4 + 3][r] = w.w;
        }
        __syncthreads();
#pragma unroll
        for (int k = 0; k < TKK; ++k) {
            float a[8], b[8];
            *(float4*)&a[0] = *(const float4*)&Xs[k][ty * 8];
            *(float4*)&a[4] = *(const float4*)&Xs[k][ty * 8 + 4];
            *(float4*)&b[0] = *(const float4*)&Ws[k][tx * 8];
            *(float4*)&b[4] = *(const float4*)&Ws[k][tx * 8 + 4];
#pragma unroll
            for (int i = 0; i < 8; ++i)
#pragma unroll
                for (int n = 0; n < 8; ++n)
                    acc[i][n] = fmaf(a[i], b[n], acc[i][n]);
        }
    }

    float bv[8];
    *(float4*)&bv[0] = *(const float4*)&bias[tx * 8];
    *(float4*)&bv[4] = *(const float4*)&bias[tx * 8 + 4];
#pragma unroll
    for (int i = 0; i < 8; ++i) {
        const size_t row = (size_t)(m0 + ty * 8 + i);
        float4 v0, v1;
        v0.x = acc[i][0] + bv[0]; v0.y = acc[i][1] + bv[1];
        v0.z = acc[i][2] + bv[2]; v0.w = acc[i][3] + bv[3];
        v1.x = acc[i][4] + bv[4]; v1.y = acc[i][5] + bv[5];
        v1.z = acc[i][6] + bv[6]; v1.w = acc[i][7] + bv[7];
        *(float4*)&out[row * HN + tx * 8]     = v0;
        *(float4*)&out[row * HN + tx * 8 + 4] = v1;
    }
}

// ---------------------------------------------------------------------------
// Phase B: wave-specialized 4-stage pipeline. One WG (512 thr, 8 waves) per
// batch row. Iteration i:
//   waves 0-1 (tid   0..127): stage1 -> s1(i)          [needs s1(i-1), ff(i)]
//   waves 2-5 (tid 128..383): stage2 -> s2(i-1)        [needs s1(i-1), s2(i-2)]
//   wave  6   (tid 384..447): stage3 -> rdot(i-2)      [needs s2(i-2)]
//   wave  7   (tid 448..511): stage4 -> om/softmax(i-3)[needs rdot(i-3)]
// Double-buffered LDS indexed by step parity; exactly ONE barrier/iteration.
// Each role runs its own loop (wave-uniform role split, balanced s_barrier
// counts) so per-role weight registers don't union in the allocator.
// ---------------------------------------------------------------------------
__global__ __launch_bounds__(512, 2) void srnn_pipe(
    const float* __restrict__ ff,
    const float* __restrict__ W_h1h1, const float* __restrict__ b_h1h1,
    const float* __restrict__ W_h1h2, const float* __restrict__ b_h1h2,
    const float* __restrict__ W_h2h2, const float* __restrict__ b_h2h2,
    const float* __restrict__ W_h2o,  const float* __restrict__ b_h2o,
    const float* __restrict__ tau_adp_h1, const float* __restrict__ tau_adp_h2,
    const float* __restrict__ tau_m_h1,   const float* __restrict__ tau_m_h2,
    const float* __restrict__ tau_m_o,
    const float* __restrict__ h1m0, const float* __restrict__ h2m0,
    const float* __restrict__ om0,
    float* __restrict__ out) {
    const int b   = blockIdx.x;
    const int tid = threadIdx.x;

    __shared__ __align__(16) float s1_lds[2][HN];
    __shared__ __align__(16) float s2_lds[2][HN];
    __shared__ __align__(16) float rdot_lds[2][32];

    if (tid < HN) {
        s1_lds[0][tid] = 0.f; s1_lds[1][tid] = 0.f;
        s2_lds[0][tid] = 0.f; s2_lds[1][tid] = 0.f;
    }
    if (tid < 32) { rdot_lds[0][tid] = 0.f; rdot_lds[1][tid] = 0.f; }

    if (tid < 128) {
        // ================= STAGE 1: layer-1 LIF =================
        const int j = tid;
        float wA[128];
#pragma unroll
        for (int kk = 0; kk < 128; kk += 4)
            *(float4*)&wA[kk] = *(const float4*)&W_h1h1[j * HN + kk];
        float h1m = h1m0[b * HN + j];
        const float a1 = expf(-1.f / tau_m_h1[j]);
        const float r1 = expf(-1.f / tau_adp_h1[j]);
        const float bias1 = b_h1h1[j];
        float b1 = 0.01f, s1p = 0.f;
        const float* ffp = ff + (size_t)b * TSTEPS * HN + j;
        float ff_c = ffp[0];
        float ff_n = ffp[HN];
        __syncthreads();
        for (int i = 0; i < TSTEPS + 3; ++i) {
            if (i < TSTEPS) {
                float ff_2 = (i + 2 < TSTEPS) ? ffp[(size_t)(i + 2) * HN] : 0.f;
                const float* sp = s1_lds[(i - 1) & 1];
                float p0 = 0.f, p1 = 0.f, p2 = 0.f, p3 = 0.f;
#pragma unroll
                for (int kk = 0; kk < 128; kk += 4) {
                    float4 s = *(const float4*)&sp[kk];
                    p0 = fmaf(s.x, wA[kk],     p0);
                    p1 = fmaf(s.y, wA[kk + 1], p1);
                    p2 = fmaf(s.z, wA[kk + 2], p2);
                    p3 = fmaf(s.w, wA[kk + 3], p3);
                }
                const float pA = (p0 + p1) + (p2 + p3);
                b1 = r1 * b1 + (1.f - r1) * s1p;
                const float Bth = 0.01f + 1.8f * b1;
                h1m = h1m * a1 + (1.f - a1) * (ff_c + bias1 + pA) - Bth * s1p;
                s1p = (h1m - Bth > 0.f) ? 1.f : 0.f;
                s1_lds[i & 1][j] = s1p;
                ff_c = ff_n; ff_n = ff_2;
            }
            __syncthreads();
        }
    } else if (tid < 384) {
        // ================= STAGE 2: layer-2 LIF =================
        const int t2 = tid - 128;
        const int j2 = t2 >> 1;
        const int hf = t2 & 1;
        float wB[64], wC[64];
#pragma unroll
        for (int kk = 0; kk < 64; kk += 4) {
            *(float4*)&wB[kk] = *(const float4*)&W_h1h2[j2 * HN + hf * 64 + kk];
            *(float4*)&wC[kk] = *(const float4*)&W_h2h2[j2 * HN + hf * 64 + kk];
        }
        float h2m = h2m0[b * HN + j2];
        const float a2 = expf(-1.f / tau_m_h2[j2]);
        const float r2 = expf(-1.f / tau_adp_h2[j2]);
        const float bias2 = b_h1h2[j2] + b_h2h2[j2];
        float b2 = 0.01f, s2p = 0.f;
        __syncthreads();
        for (int i = 0; i < TSTEPS + 3; ++i) {
            const int k = i - 1;
            if (k >= 0 && k < TSTEPS) {
                const float* sp1 = &s1_lds[k & 1][hf * 64];
                const float* sp2 = &s2_lds[(k - 1) & 1][hf * 64];
                float q0 = 0.f, q1 = 0.f, q2 = 0.f, q3 = 0.f;
                float c0 = 0.f, c1 = 0.f, c2 = 0.f, c3 = 0.f;
#pragma unroll
                for (int kk = 0; kk < 64; kk += 4) {
                    float4 s = *(const float4*)&sp1[kk];
                    float4 u = *(const float4*)&sp2[kk];
                    q0 = fmaf(s.x, wB[kk],     q0);
                    q1 = fmaf(s.y, wB[kk + 1], q1);
                    q2 = fmaf(s.z, wB[kk + 2], q2);
                    q3 = fmaf(s.w, wB[kk + 3], q3);
                    c0 = fmaf(u.x, wC[kk],     c0);
                    c1 = fmaf(u.y, wC[kk + 1], c1);
                    c2 = fmaf(u.z, wC[kk + 2], c2);
                    c3 = fmaf(u.w, wC[kk + 3], c3);
                }
                float pB = (q0 + q1) + (q2 + q3);
                float pC = (c0 + c1) + (c2 + c3);
                pB += __shfl_xor(pB, 1);
                pC += __shfl_xor(pC, 1);
                const float in2 = pB + pC + bias2;
                b2 = r2 * b2 + (1.f - r2) * s2p;
                const float Bth = 0.01f + 1.8f * b2;
                h2m = h2m * a2 + (1.f - a2) * in2 - Bth * s2p;
                s2p = (h2m - Bth > 0.f) ? 1.f : 0.f;
                if (!hf) s2_lds[k & 1][j2] = s2p;
            }
            __syncthreads();
        }
    } else if (tid < 448) {
        // ================= STAGE 3: readout matvec =================
        const int t3 = tid - 384;
        const int o3 = t3 >> 1;     // 0..31, active < 20
        const int sg = t3 & 1;
        float wO[64];
        if (o3 < ON) {
#pragma unroll
            for (int m = 0; m < 64; m += 4)
                *(float4*)&wO[m] = *(const float4*)&W_h2o[o3 * HN + sg * 64 + m];
        }
        __syncthreads();
        for (int i = 0; i < TSTEPS + 3; ++i) {
            const int k = i - 2;
            if (k >= 0 && k < TSTEPS && o3 < ON) {
                const float* sp = &s2_lds[k & 1][sg * 64];
                float r0 = 0.f, r1 = 0.f, r2 = 0.f, r3 = 0.f;
#pragma unroll
                for (int m = 0; m < 64; m += 4) {
                    float4 s = *(const float4*)&sp[m];
                    r0 = fmaf(s.x, wO[m],     r0);
                    r1 = fmaf(s.y, wO[m + 1], r1);
                    r2 = fmaf(s.z, wO[m + 2], r2);
                    r3 = fmaf(s.w, wO[m + 3], r3);
                }
                float r = (r0 + r1) + (r2 + r3);
                r += __shfl_xor(r, 1);
                if (!sg) rdot_lds[k & 1][o3] = r;
            }
            __syncthreads();
        }
    } else {
        // ================= STAGE 4: leaky readout + softmax accumulate =====
        const int o4 = tid - 448;   // 0..63, active < 20
        float om = 0.f, ao = 0.f, bo = 0.f, acc = 0.f;
        if (o4 < ON) {
            om = om0[b * ON + o4];
            ao = expf(-1.f / tau_m_o[o4]);
            bo = b_h2o[o4];
        }
        __syncthreads();
        for (int i = 0; i < TSTEPS + 3; ++i) {
            const int k = i - 3;
            if (k >= 0 && k < TSTEPS) {
                if (o4 < ON)
                    om = om * ao + (1.f - ao) * (rdot_lds[k & 1][o4] + bo);
                float mx = (o4 < ON) ? om : -3.4e38f;
#pragma unroll
                for (int m = 16; m >= 1; m >>= 1)
                    mx = fmaxf(mx, __shfl_xor(mx, m));
                float e = (o4 < ON) ? __expf(om - mx) : 0.f;
                float den = e;
#pragma unroll
                for (int m = 16; m >= 1; m >>= 1)
                    den += __shfl_xor(den, m);
                if (o4 < ON && k > 10) acc += e / den;
            }
            __syncthreads();
        }
        if (o4 < ON) out[b * ON + o4] = acc;
    }
}

// ---------------------------------------------------------------------------
// Phase C: A_norm = sum|W_h1h1| + sum|W_h2h2|  -> out[5120]
// ---------------------------------------------------------------------------
__global__ void anorm_kernel(const float* __restrict__ W1,
                             const float* __restrict__ W2,
                             float* __restrict__ out) {
    __shared__ float red[256];
    float s = 0.f;
    for (int i = threadIdx.x; i < HN * HN; i += 256)
        s += fabsf(W1[i]) + fabsf(W2[i]);
    red[threadIdx.x] = s;
    __syncthreads();
    for (int off = 128; off > 0; off >>= 1) {
        if (threadIdx.x < off) red[threadIdx.x] += red[threadIdx.x + off];
        __syncthreads();
    }
    if (threadIdx.x == 0) out[256 * ON] = red[0];
}

extern "C" void kernel_launch(void* const* d_in, const int* in_sizes, int n_in,
                              void* d_out, int out_size, void* d_ws, size_t ws_size,
                              hipStream_t stream) {
    const float* input      = (const float*)d_in[0];
    // d_in[1], d_in[2]: A1_mask/A2_mask -- all-ones, unused by reference math
    const float* W_ih1      = (const float*)d_in[3];
    const float* b_ih1      = (const float*)d_in[4];
    const float* W_h1h1     = (const float*)d_in[5];
    const float* b_h1h1     = (const float*)d_in[6];
    const float* W_h1h2     = (const float*)d_in[7];
    const float* b_h1h2     = (const float*)d_in[8];
    const float* W_h2h2     = (const float*)d_in[9];
    const float* b_h2h2     = (const float*)d_in[10];
    const float* W_h2o      = (const float*)d_in[11];
    const float* b_h2o      = (const float*)d_in[12];
    const float* tau_adp_h1 = (const float*)d_in[13];
    const float* tau_adp_h2 = (const float*)d_in[14];
    const float* tau_m_h1   = (const float*)d_in[15];
    const float* tau_m_h2   = (const float*)d_in[16];
    const float* tau_m_o    = (const float*)d_in[17];
    const float* h1m0       = (const float*)d_in[18];
    const float* h2m0       = (const float*)d_in[19];
    const float* om0        = (const float*)d_in[20];

    float* out   = (float*)d_out;
    float* ffbuf = (float*)d_ws;   // 256*250*128*4 = 32.768 MB

    // Phase C first: tiny, overlaps with the GEMM
    anorm_kernel<<<1, 256, 0, stream>>>(W_h1h1, W_h2h2, out);
    // Phase A: feedforward GEMM (64000 x 128 over K=700)
    ff_gemm<<<500, 256, 0, stream>>>(input, W_ih1, b_ih1, ffbuf);
    // Phase B: 250-step pipelined recurrence, one WG per batch row
    srnn_pipe<<<256, 512, 0, stream>>>(ffbuf, W_h1h1, b_h1h1, W_h1h2, b_h1h2,
                                       W_h2h2, b_h2h2, W_h2o, b_h2o,
                                       tau_adp_h1, tau_adp_h2,
                                       tau_m_h1, tau_m_h2, tau_m_o,
                                       h1m0, h2m0, om0, out);
}